// Round 5
// baseline (915.771 us; speedup 1.0000x reference)
//
#include <hip/hip_runtime.h>

// CALIBRATION ROUND (R5): R1's exact scan executed 8x per launch.
// Passes 0..6 write spikes to d_ws (sink, never validated but not DSE-able:
// sink ptr is not __restrict__, pass loop is not unrolled); pass 7 writes
// d_out (bit-identical values -> correctness preserved).
// Purpose: (a) K1 = (dur_us - 392)/7 separates kernel time from the
// suspected ~375us fixed harness-restore overhead; (b) the 8x kernel
// dispatch (~8*K1) exceeds the 158us rocprof top-5 cutoff, exposing the
// kernel's own FETCH_SIZE / hbm_gbps for the first time.
//
// Numerics: per-pass body is byte-for-byte R1's verified-bit-exact scan.

#define TT 1024
#define NN 1024
#define BB 32
#define UU 16   // time-steps per prefetch chunk
#define PASSES 8

__global__ __launch_bounds__(64, 1)
void lif_scan_kernel(const float* __restrict__ in, float* __restrict__ out,
                     float* sink) {
    const int gid = blockIdx.x * 64 + threadIdx.x;   // 0 .. 32767
    const int b = gid >> 10;
    const int n = gid & (NN - 1);

    const float* __restrict__ ip = in + (size_t)b * TT * 2 * NN + n;
    const size_t obase = (size_t)b * TT * NN + n;

    const float SD0 = 0.25f;   // 2^-2  (tau_syn=5)
    const float SD1 = 0.5f;    // 2^-1  (tau_syn=2)
    const float MD  = 0.125f;  // 2^-3  (tau_mem=10)

#pragma unroll 1
    for (int pass = 0; pass < PASSES; ++pass) {
        float* op = ((pass == PASSES - 1) ? out : sink) + obase;

        float i0 = 0.0f, i1 = 0.0f, v = 0.0f;

        float x0[UU], x1[UU];
#pragma unroll
        for (int j = 0; j < UU; ++j) {
            x0[j] = ip[j * 2048];
            x1[j] = ip[j * 2048 + 1024];
        }

        for (int tc = 0; tc < TT - UU; tc += UU) {
            float y0[UU], y1[UU];
            const float* pn = ip + (size_t)(tc + UU) * 2048;
#pragma unroll
            for (int j = 0; j < UU; ++j) {
                y0[j] = pn[j * 2048];
                y1[j] = pn[j * 2048 + 1024];
            }
            float* po = op + (size_t)tc * NN;
#pragma unroll
            for (int j = 0; j < UU; ++j) {
                i0 = (i0 - i0 * SD0) + x0[j];
                i1 = (i1 - i1 * SD1) + x1[j];
                float vd = v - v * MD;
                v = vd + (i0 + i1);
                float spk = (v >= 1.0f) ? 1.0f : 0.0f;
                v -= spk;                      // membrane-subtract reset
                po[j * NN] = spk;
            }
#pragma unroll
            for (int j = 0; j < UU; ++j) { x0[j] = y0[j]; x1[j] = y1[j]; }
        }

        {   // epilogue: last chunk
            float* po = op + (size_t)(TT - UU) * NN;
#pragma unroll
            for (int j = 0; j < UU; ++j) {
                i0 = (i0 - i0 * SD0) + x0[j];
                i1 = (i1 - i1 * SD1) + x1[j];
                float vd = v - v * MD;
                v = vd + (i0 + i1);
                float spk = (v >= 1.0f) ? 1.0f : 0.0f;
                v -= spk;
                po[j * NN] = spk;
            }
        }
    }
}

extern "C" void kernel_launch(void* const* d_in, const int* in_sizes, int n_in,
                              void* d_out, int out_size, void* d_ws, size_t ws_size,
                              hipStream_t stream) {
    const float* in = (const float*)d_in[0];
    float* out = (float*)d_out;
    // Sink for the 7 calibration passes: d_ws if it can hold 128 MiB of
    // spikes, else d_out (still correct: all passes write identical values).
    float* sink = (ws_size >= (size_t)BB * TT * NN * sizeof(float))
                      ? (float*)d_ws : out;
    dim3 grid(BB * NN / 64);   // 512 one-wave blocks
    dim3 block(64);
    hipLaunchKernelGGL(lif_scan_kernel, grid, block, 0, stream, in, out, sink);
}

// Round 6
// 397.631 us; speedup vs baseline: 2.3031x; 2.3031x over previous
//
#include <hip/hip_runtime.h>

// LIF bitshift-decay scan: B=32, T=1024, N=1024, n_syn=2. fp32, bit-exact.
//
// R5 calibration: kernel is ~80us; wall carries ~312us fixed harness restore.
// Counters: FETCH 132MB + L3-served 136MB reads, WRITE 134MB, effective
// 5.0 TB/s. R1's double-buffer drains vmcnt to 0 every chunk (x=y copy) ->
// avg in-flight only ~16 loads/wave. R6: modulo-4 register pipeline, no
// copies: compute chunk c while chunks c+1..c+3 (24 loads) remain in flight.
// 8-step chunks, 128 chunks; 48 loads + 8 stores = 56 < vmcnt depth 63.
//
// Numerics: identical expression order to the verified-bit-exact R1:
//   i = (i - i*sd) + x;  v = (v - v*md) + (i0 + i1);  spike-subtract 1.0.

#define TT 1024
#define NN 1024
#define BB 32
#define UU 8                 // time-steps per chunk
#define NCHUNK (TT / UU)     // 128 chunks

__global__ __launch_bounds__(64, 1)
void lif_scan_kernel(const float* __restrict__ in, float* __restrict__ out) {
    const int gid = blockIdx.x * 64 + threadIdx.x;   // 0 .. 32767
    const int b = gid >> 10;
    const int n = gid & (NN - 1);

    const float* __restrict__ ip = in  + (size_t)b * TT * 2 * NN + n;
    float* __restrict__       op = out + (size_t)b * TT * NN     + n;

    const float SD0 = 0.25f;   // 2^-2  (tau_syn=5)
    const float SD1 = 0.5f;    // 2^-1  (tau_syn=2)
    const float MD  = 0.125f;  // 2^-3  (tau_mem=10)

    float i0 = 0.0f, i1 = 0.0f, v = 0.0f;

    // four chunk buffers (modulo-4 pipeline, no inter-buffer copies)
    float a0[UU], a1[UU], b0[UU], b1[UU],
          c0[UU], c1[UU], d0[UU], d1[UU];

#define LOADC(B0, B1, CH)                                            \
    {                                                                \
        const float* _p = ip + (size_t)(CH) * (UU * 2048);           \
        _Pragma("unroll")                                            \
        for (int j = 0; j < UU; ++j) {                               \
            B0[j] = _p[j * 2048];                                    \
            B1[j] = _p[j * 2048 + 1024];                             \
        }                                                            \
    }

#define COMPC(B0, B1, CH)                                            \
    {                                                                \
        float* _o = op + (size_t)(CH) * (UU * NN);                   \
        _Pragma("unroll")                                            \
        for (int j = 0; j < UU; ++j) {                               \
            i0 = (i0 - i0 * SD0) + B0[j];                            \
            i1 = (i1 - i1 * SD1) + B1[j];                            \
            float vd = v - v * MD;                                   \
            v = vd + (i0 + i1);                                      \
            float spk = (v >= 1.0f) ? 1.0f : 0.0f;                   \
            v -= spk;                    /* membrane-subtract */     \
            _o[j * NN] = spk;                                        \
        }                                                            \
    }

    // prologue: fill the pipeline with chunks 0..3 (64 loads issued)
    LOADC(a0, a1, 0)
    LOADC(b0, b1, 1)
    LOADC(c0, c1, 2)
    LOADC(d0, d1, 3)

    // steady state: compute chunk c (waits only its 16 loads; 24 loads of
    // chunks c+1..c+3 stay in flight), then refill its buffer with c+4.
    for (int c = 0; c < NCHUNK - 4; c += 4) {
        COMPC(a0, a1, c)     LOADC(a0, a1, c + 4)
        COMPC(b0, b1, c + 1) LOADC(b0, b1, c + 5)
        COMPC(c0, c1, c + 2) LOADC(c0, c1, c + 6)
        COMPC(d0, d1, c + 3) LOADC(d0, d1, c + 7)
    }

    // epilogue: last 4 chunks
    COMPC(a0, a1, NCHUNK - 4)
    COMPC(b0, b1, NCHUNK - 3)
    COMPC(c0, c1, NCHUNK - 2)
    COMPC(d0, d1, NCHUNK - 1)

#undef LOADC
#undef COMPC
}

extern "C" void kernel_launch(void* const* d_in, const int* in_sizes, int n_in,
                              void* d_out, int out_size, void* d_ws, size_t ws_size,
                              hipStream_t stream) {
    const float* in = (const float*)d_in[0];
    float* out = (float*)d_out;
    dim3 grid(BB * NN / 64);   // 512 one-wave blocks -> 2 waves/CU
    dim3 block(64);
    hipLaunchKernelGGL(lif_scan_kernel, grid, block, 0, stream, in, out);
}